// Round 3
// baseline (455.927 us; speedup 1.0000x reference)
//
#include <hip/hip_runtime.h>

// MDI_2422361555492 on gfx950 — R5: pin the register budget, fence the scheduler.
// rocprof R4: WRITE_SIZE still 423 MB (~400 B/thread scratch) with VGPR_Count=64
// under __launch_bounds__(256,4). Diagnosis: launch_bounds arg2 is only a MIN —
// the allocator targeted 8 waves/EU (64 regs) and spilled. Observed occupancy
// 41% ~= 16 waves/CU matches 64 arch + 64 acc per wave. Also the fully-unrolled
// straight line lets the scheduler hoist 32 float4 loads (128 VGPRs of dests)
// and cross-section frag ds_reads, inflating live ranges past the ~110-reg
// true peak.
// R5 (math/layout identical to R4, which passed):
//   1. __attribute__((amdgpu_waves_per_eu(4,4))) — min AND max pinned, so the
//      allocator uses the full 128-reg budget instead of squeezing to 64.
//   2. __builtin_amdgcn_sched_barrier(0) after each load-slot / GEMM section —
//      caps in-flight loads per wave; TLP (16 waves/CU) covers the latency.
// Layout invariants (unchanged):
//   B slot (m,g=lane>>4,j) holds x[row=lane&15][col = 32m+16(j>>2)+4g+(j&3)]
//   A frag (cb,m,lane,j)   holds W[32m+16(j>>2)+4(lane>>4)+(j&3)][16cb+(lane&15)]
//   D (cb, reg q, lane)    = (X@W)[lane&15][16cb+4g+q]
//   chaining: out slot (cb,q) == input slot (m'=cb>>1, j'=4(cb&1)+q) (same lane)

typedef __attribute__((ext_vector_type(8))) short short8;
typedef __attribute__((ext_vector_type(4))) float f32x4;
typedef unsigned int u32;

#define MF(W, X, A) __builtin_amdgcn_mfma_f32_16x16x32_bf16((W), (X), (A), 0, 0, 0)
#define SBAR0 __builtin_amdgcn_sched_barrier(0)

__device__ __forceinline__ short bf16rne(float f) {
    u32 u = __builtin_bit_cast(u32, f);
    u = (u + 0x7fffu + ((u >> 16) & 1u)) >> 16;
    return (short)u;
}
__device__ __forceinline__ float bf2f(short s) {
    u32 u = ((u32)(unsigned short)s) << 16;
    return __builtin_bit_cast(float, u);
}

// ---- prologue: pack 6 matrices into pi-permuted bf16 A-fragments ----
// mat order: 0=W_gcn 1=M_m 2=Wv_m 3=M_d 4=Wv_d 5=W1
// dst[mat*16384 + ((cb*4+m)*64+lane)*8 + j]
//   = bf16( W[32m+16*(j>>2)+4*(lane>>4)+(j&3)][16cb+(lane&15)] )
// mats 1/3: W = M = Wq@Wk^T computed on the fly (bijective, zero redundancy).
__global__ void k_pack(const float* __restrict__ W_gcn,
                       const float* __restrict__ Wq_m, const float* __restrict__ Wk_m,
                       const float* __restrict__ Wv_m,
                       const float* __restrict__ Wq_d, const float* __restrict__ Wk_d,
                       const float* __restrict__ Wv_d, const float* __restrict__ W1,
                       unsigned short* __restrict__ dst) {
    const int idx  = blockIdx.x * 256 + threadIdx.x;   // 98304 = 6*16384
    const int mat  = idx >> 14;
    const int rem  = idx & 16383;
    const int j    = rem & 7;
    const int lane = (rem >> 3) & 63;
    const int m    = (rem >> 9) & 3;
    const int cb   = rem >> 11;
    const int rowk = 32 * m + 16 * (j >> 2) + 4 * ((lane >> 4) & 3) + (j & 3);
    const int col  = 16 * cb + (lane & 15);
    float v;
    if (mat == 1 || mat == 3) {
        const float* Q = (mat == 1) ? Wq_m : Wq_d;
        const float* K = (mat == 1) ? Wk_m : Wk_d;
        float s = 0.f;
#pragma unroll 8
        for (int c = 0; c < 128; c += 4) {
            float4 qa = *(const float4*)(Q + rowk * 128 + c);
            float4 kb = *(const float4*)(K + col * 128 + c);
            s += qa.x * kb.x + qa.y * kb.y + qa.z * kb.z + qa.w * kb.w;
        }
        v = s;
    } else {
        const float* W = (mat == 0) ? W_gcn : (mat == 2) ? Wv_m : (mat == 4) ? Wv_d : W1;
        v = W[rowk * 128 + col];
    }
    u32 u = __builtin_bit_cast(u32, v);
    u = (u + 0x7fffu + ((u >> 16) & 1u)) >> 16;
    dst[idx] = (unsigned short)u;
}

// ---- static-index helpers (no runtime vector subscripts anywhere) ----
template<int JB>
__device__ __forceinline__ void gcn_store(short8& t1d, short8& t2d,
                                          const short8& emo, const short8& edo,
                                          f32x4 gm, f32x4 gd, float pa, float pb) {
#define GCN_Q(Qi)                                                          \
    { float vm = pa * gm[Qi] + pb * gd[Qi];                                \
      float vd = pb * gm[Qi] + pa * gd[Qi];                                \
      vm = vm > 0.f ? vm : 0.f; vd = vd > 0.f ? vd : 0.f;                  \
      t1d[JB + Qi] = bf16rne(vm + bf2f(emo[JB + Qi]));                     \
      t2d[JB + Qi] = bf16rne(vd + bf2f(edo[JB + Qi])); }
    GCN_Q(0) GCN_Q(1) GCN_Q(2) GCN_Q(3)
#undef GCN_Q
}

template<int JB>
__device__ __forceinline__ void dot_acc(f32x4 a, const short8& e, const short8& t,
                                        float& l0, float& l1) {
    l0 += a[0] * bf2f(e[JB + 0]) + a[1] * bf2f(e[JB + 1])
        + a[2] * bf2f(e[JB + 2]) + a[3] * bf2f(e[JB + 3]);
    l1 += a[0] * bf2f(t[JB + 0]) + a[1] * bf2f(t[JB + 1])
        + a[2] * bf2f(t[JB + 2]) + a[3] * bf2f(t[JB + 3]);
}

template<int JB>
__device__ __forceinline__ void store4(short8& d, f32x4 a) {
    d[JB + 0] = bf16rne(a[0]); d[JB + 1] = bf16rne(a[1]);
    d[JB + 2] = bf16rne(a[2]); d[JB + 3] = bf16rne(a[3]);
}

template<int JB>
__device__ __forceinline__ void mul_store(short8& d, const short8& mla, f32x4 a) {
    d[JB + 0] = bf16rne(bf2f(mla[JB + 0]) * a[0]);
    d[JB + 1] = bf16rne(bf2f(mla[JB + 1]) * a[1]);
    d[JB + 2] = bf16rne(bf2f(mla[JB + 2]) * a[2]);
    d[JB + 3] = bf16rne(bf2f(mla[JB + 3]) * a[3]);
}

__device__ __forceinline__ short8 mix8(const short8& prev, const short8& cur,
                                       float aw0, float aw1) {
    short8 r;
    r[0] = bf16rne(aw0 * bf2f(prev[0]) + aw1 * bf2f(cur[0]));
    r[1] = bf16rne(aw0 * bf2f(prev[1]) + aw1 * bf2f(cur[1]));
    r[2] = bf16rne(aw0 * bf2f(prev[2]) + aw1 * bf2f(cur[2]));
    r[3] = bf16rne(aw0 * bf2f(prev[3]) + aw1 * bf2f(cur[3]));
    r[4] = bf16rne(aw0 * bf2f(prev[4]) + aw1 * bf2f(cur[4]));
    r[5] = bf16rne(aw0 * bf2f(prev[5]) + aw1 * bf2f(cur[5]));
    r[6] = bf16rne(aw0 * bf2f(prev[6]) + aw1 * bf2f(cur[6]));
    r[7] = bf16rne(aw0 * bf2f(prev[7]) + aw1 * bf2f(cur[7]));
    return r;
}

// stats + bf16 pack for one 32-col slot (two f32x4 halves), non-temporal loads
__device__ __forceinline__ void load_slot(const float* pm, const float* pd,
                                          short8& e8m, short8& e8d,
                                          float& s_mm, float& s_dd,
                                          float& s_md, float& s_ab) {
    f32x4 a0 = __builtin_nontemporal_load((const f32x4*)pm);
    f32x4 a1 = __builtin_nontemporal_load((const f32x4*)(pm + 16));
    f32x4 b0 = __builtin_nontemporal_load((const f32x4*)pd);
    f32x4 b1 = __builtin_nontemporal_load((const f32x4*)(pd + 16));
#define ST(Av, Bv, Ii)                                                     \
    s_mm += Av[Ii] * Av[Ii]; s_dd += Bv[Ii] * Bv[Ii];                      \
    s_md += Av[Ii] * Bv[Ii]; s_ab += fabsf(Av[Ii] - Bv[Ii]);
    ST(a0, b0, 0) ST(a0, b0, 1) ST(a0, b0, 2) ST(a0, b0, 3)
    ST(a1, b1, 0) ST(a1, b1, 1) ST(a1, b1, 2) ST(a1, b1, 3)
#undef ST
    e8m[0] = bf16rne(a0[0]); e8m[1] = bf16rne(a0[1]);
    e8m[2] = bf16rne(a0[2]); e8m[3] = bf16rne(a0[3]);
    e8m[4] = bf16rne(a1[0]); e8m[5] = bf16rne(a1[1]);
    e8m[6] = bf16rne(a1[2]); e8m[7] = bf16rne(a1[3]);
    e8d[0] = bf16rne(b0[0]); e8d[1] = bf16rne(b0[1]);
    e8d[2] = bf16rne(b0[2]); e8d[3] = bf16rne(b0[3]);
    e8d[4] = bf16rne(b1[0]); e8d[5] = bf16rne(b1[1]);
    e8d[6] = bf16rne(b1[2]); e8d[7] = bf16rne(b1[3]);
}

__global__ __launch_bounds__(256)
__attribute__((amdgpu_waves_per_eu(4, 4)))
void k_main(const float* __restrict__ em, const float* __restrict__ ed,
            const unsigned short* __restrict__ frags,
            const float* __restrict__ w2, float* __restrict__ out) {
    __shared__ short8 lfr[2048];                       // 32 KB single staging buffer
    const int tid  = threadIdx.x;
    const int lane = tid & 63;
    const int g    = (lane >> 4) & 3;                  // k-group / col sub-offset
    const int rs   = lane & 15;                        // row within wave
    const int wv   = tid >> 6;                         // wave in block
    const long row = ((long)blockIdx.x * 4 + wv) * 16 + rs;
    const float* emr = em + row * 128;
    const float* edr = ed + row * 128;

    // stage matrix `mat` (32 KB) into lfr; LDS dest wave-uniform base + lane*16
    auto STAGE = [&](int mat) {
        const unsigned short* src = frags + mat * 16384;
        unsigned short* lb = (unsigned short*)lfr;
#pragma unroll
        for (int w = 0; w < 8; ++w) {
            const int ch = wv * 8 + w;                 // 32 chunks x 1 KB
            __builtin_amdgcn_global_load_lds(
                (const __attribute__((address_space(1))) u32*)(src + ch * 512 + lane * 8),
                (__attribute__((address_space(3))) u32*)(lb + ch * 512), 16, 0, 0);
        }
    };

    STAGE(0);                                          // W_gcn, overlaps em/ed stream

    // ---- load em/ed (slot order), adjacency stats on the fly ----
    short8 em_0, em_1, em_2, em_3, ed_0, ed_1, ed_2, ed_3;
    float s_mm = 0.f, s_dd = 0.f, s_md = 0.f, s_ab = 0.f;
    load_slot(emr +  0 + 4 * g, edr +  0 + 4 * g, em_0, ed_0, s_mm, s_dd, s_md, s_ab);
    SBAR0;
    load_slot(emr + 32 + 4 * g, edr + 32 + 4 * g, em_1, ed_1, s_mm, s_dd, s_md, s_ab);
    SBAR0;
    load_slot(emr + 64 + 4 * g, edr + 64 + 4 * g, em_2, ed_2, s_mm, s_dd, s_md, s_ab);
    SBAR0;
    load_slot(emr + 96 + 4 * g, edr + 96 + 4 * g, em_3, ed_3, s_mm, s_dd, s_md, s_ab);
    SBAR0;

    // per-row reduce across the 4 g-groups (lanes l, l^16, l^32, l^48)
    s_mm += __shfl_xor(s_mm, 16); s_mm += __shfl_xor(s_mm, 32);
    s_dd += __shfl_xor(s_dd, 16); s_dd += __shfl_xor(s_dd, 32);
    s_md += __shfl_xor(s_md, 16); s_md += __shfl_xor(s_md, 32);
    s_ab += __shfl_xor(s_ab, 16); s_ab += __shfl_xor(s_ab, 32);

    // adjacency closed form: pL = min(pL_cos, pL_manh), both [[a,b],[b,a]]
    const float a3 = 1.f / (1.f + s_ab);               // manh off-diag >=0, lrelu=id
    const float b3 = s_ab * a3;
    float cosv = s_md * rsqrtf((s_mm + 1e-8f) * (s_dd + 1e-8f));
    float cl = cosv < 0.f ? 0.01f * cosv : cosv;       // leaky_relu 0.01
    const float a1n = 1.f / (1.f + cl);
    const float b1 = cl * a1n;
    const float pa = fminf(a1n, a3);
    const float pb = fminf(b1, b3);

    __syncthreads();                                   // W_gcn staged

    // one C-column-block GEMM: a += frag(cb,m) * x_m
#define GEMM8(CB, X0, X1, X2, X3, A)                                       \
    { A = MF(lfr[((CB) * 4 + 0) * 64 + lane], X0, A);                      \
      A = MF(lfr[((CB) * 4 + 1) * 64 + lane], X1, A);                      \
      A = MF(lfr[((CB) * 4 + 2) * 64 + lane], X2, A);                      \
      A = MF(lfr[((CB) * 4 + 3) * 64 + lane], X3, A); }

    // ---- GCN: gm=em@W, gd=ed@W from ORIGINALS; x1 -> x1m_*/x1d_* ----
    short8 x1m_0, x1m_1, x1m_2, x1m_3, x1d_0, x1d_1, x1d_2, x1d_3;
#define SEC_GCN(CB, JB, T1D, T2D, EMO, EDO)                                \
    { f32x4 gm = {0.f, 0.f, 0.f, 0.f}, gd = {0.f, 0.f, 0.f, 0.f};          \
      { const short8 w0 = lfr[((CB) * 4 + 0) * 64 + lane];                 \
        const short8 w1 = lfr[((CB) * 4 + 1) * 64 + lane];                 \
        const short8 wA = lfr[((CB) * 4 + 2) * 64 + lane];                 \
        const short8 wB = lfr[((CB) * 4 + 3) * 64 + lane];                 \
        gm = MF(w0, em_0, gm); gd = MF(w0, ed_0, gd);                      \
        gm = MF(w1, em_1, gm); gd = MF(w1, ed_1, gd);                      \
        gm = MF(wA, em_2, gm); gd = MF(wA, ed_2, gd);                      \
        gm = MF(wB, em_3, gm); gd = MF(wB, ed_3, gd); }                    \
      gcn_store<JB>(T1D, T2D, EMO, EDO, gm, gd, pa, pb); }                 \
    SBAR0;
    SEC_GCN(0, 0, x1m_0, x1d_0, em_0, ed_0)
    SEC_GCN(1, 4, x1m_0, x1d_0, em_0, ed_0)
    SEC_GCN(2, 0, x1m_1, x1d_1, em_1, ed_1)
    SEC_GCN(3, 4, x1m_1, x1d_1, em_1, ed_1)
    SEC_GCN(4, 0, x1m_2, x1d_2, em_2, ed_2)
    SEC_GCN(5, 4, x1m_2, x1d_2, em_2, ed_2)
    SEC_GCN(6, 0, x1m_3, x1d_3, em_3, ed_3)
    SEC_GCN(7, 4, x1m_3, x1d_3, em_3, ed_3)
#undef SEC_GCN

    __syncthreads(); STAGE(1); __syncthreads();        // M_m

    const float isq = 0.08838834764831845f;            // 1/sqrt(128)

    // ---- m attention: logits via t = x1_m@M_m ----
    float l0 = 0.f, l1 = 0.f;
#define SEC_LOG(CB, JB, EO, TT, LA, LB)                                    \
    { f32x4 a = {0.f, 0.f, 0.f, 0.f};                                      \
      GEMM8(CB, x1m_0, x1m_1, x1m_2, x1m_3, a)                             \
      dot_acc<JB>(a, EO, TT, LA, LB); }                                    \
    SBAR0;
    SEC_LOG(0, 0, em_0, x1m_0, l0, l1)
    SEC_LOG(1, 4, em_0, x1m_0, l0, l1)
    SEC_LOG(2, 0, em_1, x1m_1, l0, l1)
    SEC_LOG(3, 4, em_1, x1m_1, l0, l1)
    SEC_LOG(4, 0, em_2, x1m_2, l0, l1)
    SEC_LOG(5, 4, em_2, x1m_2, l0, l1)
    SEC_LOG(6, 0, em_3, x1m_3, l0, l1)
    SEC_LOG(7, 4, em_3, x1m_3, l0, l1)
#undef SEC_LOG
    l0 += __shfl_xor(l0, 16); l0 += __shfl_xor(l0, 32);
    l1 += __shfl_xor(l1, 16); l1 += __shfl_xor(l1, 32);
    l0 *= isq; l1 *= isq;
    {
        float mx = fmaxf(l0, l1);
        float e0 = __expf(l0 - mx), e1 = __expf(l1 - mx);
        float inv = 1.f / (e0 + e1);
        float aw0 = e0 * inv, aw1 = e1 * inv;
        x1m_0 = mix8(em_0, x1m_0, aw0, aw1);
        x1m_1 = mix8(em_1, x1m_1, aw0, aw1);
        x1m_2 = mix8(em_2, x1m_2, aw0, aw1);
        x1m_3 = mix8(em_3, x1m_3, aw0, aw1);
    }
    __syncthreads(); STAGE(2); __syncthreads();        // Wv_m

    // ---- mLA = mix@Wv_m -> em_* (em dead past this point) ----
#define SEC_MLA(CB, JB, DEST)                                              \
    { f32x4 a = {0.f, 0.f, 0.f, 0.f};                                      \
      GEMM8(CB, x1m_0, x1m_1, x1m_2, x1m_3, a)                             \
      store4<JB>(DEST, a); }                                               \
    SBAR0;
    SEC_MLA(0, 0, em_0) SEC_MLA(1, 4, em_0)
    SEC_MLA(2, 0, em_1) SEC_MLA(3, 4, em_1)
    SEC_MLA(4, 0, em_2) SEC_MLA(5, 4, em_2)
    SEC_MLA(6, 0, em_3) SEC_MLA(7, 4, em_3)
#undef SEC_MLA
    __syncthreads(); STAGE(3); __syncthreads();        // M_d

    // ---- d attention ----
    float l0d = 0.f, l1d = 0.f;
#define SEC_LOGD(CB, JB, EO, TT)                                           \
    { f32x4 a = {0.f, 0.f, 0.f, 0.f};                                      \
      GEMM8(CB, x1d_0, x1d_1, x1d_2, x1d_3, a)                             \
      dot_acc<JB>(a, EO, TT, l0d, l1d); }                                  \
    SBAR0;
    SEC_LOGD(0, 0, ed_0, x1d_0)
    SEC_LOGD(1, 4, ed_0, x1d_0)
    SEC_LOGD(2, 0, ed_1, x1d_1)
    SEC_LOGD(3, 4, ed_1, x1d_1)
    SEC_LOGD(4, 0, ed_2, x1d_2)
    SEC_LOGD(5, 4, ed_2, x1d_2)
    SEC_LOGD(6, 0, ed_3, x1d_3)
    SEC_LOGD(7, 4, ed_3, x1d_3)
#undef SEC_LOGD
    l0d += __shfl_xor(l0d, 16); l0d += __shfl_xor(l0d, 32);
    l1d += __shfl_xor(l1d, 16); l1d += __shfl_xor(l1d, 32);
    l0d *= isq; l1d *= isq;
    {
        float mx = fmaxf(l0d, l1d);
        float e0 = __expf(l0d - mx), e1 = __expf(l1d - mx);
        float inv = 1.f / (e0 + e1);
        float aw0 = e0 * inv, aw1 = e1 * inv;
        x1d_0 = mix8(ed_0, x1d_0, aw0, aw1);
        x1d_1 = mix8(ed_1, x1d_1, aw0, aw1);
        x1d_2 = mix8(ed_2, x1d_2, aw0, aw1);
        x1d_3 = mix8(ed_3, x1d_3, aw0, aw1);
    }
    __syncthreads(); STAGE(4); __syncthreads();        // Wv_d

    // ---- dLA fused with ne = mLA*dLA -> x1m_* ----
#define SEC_DLA(CB, JB, MLA, DEST)                                         \
    { f32x4 a = {0.f, 0.f, 0.f, 0.f};                                      \
      GEMM8(CB, x1d_0, x1d_1, x1d_2, x1d_3, a)                             \
      mul_store<JB>(DEST, MLA, a); }                                       \
    SBAR0;
    SEC_DLA(0, 0, em_0, x1m_0) SEC_DLA(1, 4, em_0, x1m_0)
    SEC_DLA(2, 0, em_1, x1m_1) SEC_DLA(3, 4, em_1, x1m_1)
    SEC_DLA(4, 0, em_2, x1m_2) SEC_DLA(5, 4, em_2, x1m_2)
    SEC_DLA(6, 0, em_3, x1m_3) SEC_DLA(7, 4, em_3, x1m_3)
#undef SEC_DLA
    __syncthreads(); STAGE(5); __syncthreads();        // W1

    // ---- head: pre = relu(ne@W1) . w2 ; out = sigmoid(pre) ----
    float pre = 0.f;
#define SEC_HEAD(CB)                                                       \
    { f32x4 a = {0.f, 0.f, 0.f, 0.f};                                      \
      GEMM8(CB, x1m_0, x1m_1, x1m_2, x1m_3, a)                             \
      f32x4 wq = *(const f32x4*)(w2 + 16 * (CB) + 4 * g);                  \
      pre += fmaxf(a[0], 0.f) * wq[0] + fmaxf(a[1], 0.f) * wq[1]           \
           + fmaxf(a[2], 0.f) * wq[2] + fmaxf(a[3], 0.f) * wq[3]; }        \
    SBAR0;
    SEC_HEAD(0) SEC_HEAD(1) SEC_HEAD(2) SEC_HEAD(3)
    SEC_HEAD(4) SEC_HEAD(5) SEC_HEAD(6) SEC_HEAD(7)
#undef SEC_HEAD
#undef GEMM8
    pre += __shfl_xor(pre, 16); pre += __shfl_xor(pre, 32);
    if (g == 0) out[row] = 1.f / (1.f + __expf(-pre));
}

extern "C" void kernel_launch(void* const* d_in, const int* in_sizes, int n_in,
                              void* d_out, int out_size, void* d_ws, size_t ws_size,
                              hipStream_t stream) {
    const float* em    = (const float*)d_in[0];
    const float* ed    = (const float*)d_in[1];
    const float* W_gcn = (const float*)d_in[2];
    const float* Wq_m  = (const float*)d_in[3];
    const float* Wk_m  = (const float*)d_in[4];
    const float* Wv_m  = (const float*)d_in[5];
    const float* Wq_d  = (const float*)d_in[6];
    const float* Wk_d  = (const float*)d_in[7];
    const float* Wv_d  = (const float*)d_in[8];
    const float* W1    = (const float*)d_in[9];
    const float* W2    = (const float*)d_in[10];
    float* out = (float*)d_out;

    unsigned short* frags = (unsigned short*)d_ws;     // 6*16384 bf16 = 192 KB

    const int B = in_sizes[0] / 128;                   // 262144

    hipLaunchKernelGGL(k_pack, dim3(384), dim3(256), 0, stream,
                       W_gcn, Wq_m, Wk_m, Wv_m, Wq_d, Wk_d, Wv_d, W1, frags);
    hipLaunchKernelGGL(k_main, dim3(B / 64), dim3(256), 0, stream,
                       em, ed, frags, W2, out);
}

// Round 4
// 371.401 us; speedup vs baseline: 1.2276x; 1.2276x over previous
//
#include <hip/hip_runtime.h>

// MDI_2422361555492 on gfx950 — R6: give the arch-VGPR partition room.
// rocprof R5 == R4 bit-identical (VGPR 64, WRITE 422 MB): waves_per_eu(4,4)
// compiled identically to the default => the kernel was ALREADY at a 128-reg
// total budget, split 64 arch / 64 accum (VGPR_Count reports arch only).
// MFMA A/B operands + the 16 live short8 state regs need ~110 ARCH regs,
// vs 64 allotted => the persistent ~400 B/thread spill.
// R6: amdgpu_waves_per_eu(2,4) — min 2 waves/EU => 256-reg total budget, so
// the need-driven split can give the arch side ~110-170 regs. Occupancy will
// drop to ~3 waves/EU (VGPR-limited) which still saturates HBM once the
// scratch traffic is gone (270 MB mandatory => ~45 us floor).
// Math/layout identical to R4/R5 (both passed).
// Layout invariants (unchanged):
//   B slot (m,g=lane>>4,j) holds x[row=lane&15][col = 32m+16(j>>2)+4g+(j&3)]
//   A frag (cb,m,lane,j)   holds W[32m+16(j>>2)+4(lane>>4)+(j&3)][16cb+(lane&15)]
//   D (cb, reg q, lane)    = (X@W)[lane&15][16cb+4g+q]
//   chaining: out slot (cb,q) == input slot (m'=cb>>1, j'=4(cb&1)+q) (same lane)

typedef __attribute__((ext_vector_type(8))) short short8;
typedef __attribute__((ext_vector_type(4))) float f32x4;
typedef unsigned int u32;

#define MF(W, X, A) __builtin_amdgcn_mfma_f32_16x16x32_bf16((W), (X), (A), 0, 0, 0)
#define SBAR0 __builtin_amdgcn_sched_barrier(0)

__device__ __forceinline__ short bf16rne(float f) {
    u32 u = __builtin_bit_cast(u32, f);
    u = (u + 0x7fffu + ((u >> 16) & 1u)) >> 16;
    return (short)u;
}
__device__ __forceinline__ float bf2f(short s) {
    u32 u = ((u32)(unsigned short)s) << 16;
    return __builtin_bit_cast(float, u);
}

// ---- prologue: pack 6 matrices into pi-permuted bf16 A-fragments ----
// mat order: 0=W_gcn 1=M_m 2=Wv_m 3=M_d 4=Wv_d 5=W1
// dst[mat*16384 + ((cb*4+m)*64+lane)*8 + j]
//   = bf16( W[32m+16*(j>>2)+4*(lane>>4)+(j&3)][16cb+(lane&15)] )
// mats 1/3: W = M = Wq@Wk^T computed on the fly (bijective, zero redundancy).
__global__ void k_pack(const float* __restrict__ W_gcn,
                       const float* __restrict__ Wq_m, const float* __restrict__ Wk_m,
                       const float* __restrict__ Wv_m,
                       const float* __restrict__ Wq_d, const float* __restrict__ Wk_d,
                       const float* __restrict__ Wv_d, const float* __restrict__ W1,
                       unsigned short* __restrict__ dst) {
    const int idx  = blockIdx.x * 256 + threadIdx.x;   // 98304 = 6*16384
    const int mat  = idx >> 14;
    const int rem  = idx & 16383;
    const int j    = rem & 7;
    const int lane = (rem >> 3) & 63;
    const int m    = (rem >> 9) & 3;
    const int cb   = rem >> 11;
    const int rowk = 32 * m + 16 * (j >> 2) + 4 * ((lane >> 4) & 3) + (j & 3);
    const int col  = 16 * cb + (lane & 15);
    float v;
    if (mat == 1 || mat == 3) {
        const float* Q = (mat == 1) ? Wq_m : Wq_d;
        const float* K = (mat == 1) ? Wk_m : Wk_d;
        float s = 0.f;
#pragma unroll 8
        for (int c = 0; c < 128; c += 4) {
            float4 qa = *(const float4*)(Q + rowk * 128 + c);
            float4 kb = *(const float4*)(K + col * 128 + c);
            s += qa.x * kb.x + qa.y * kb.y + qa.z * kb.z + qa.w * kb.w;
        }
        v = s;
    } else {
        const float* W = (mat == 0) ? W_gcn : (mat == 2) ? Wv_m : (mat == 4) ? Wv_d : W1;
        v = W[rowk * 128 + col];
    }
    u32 u = __builtin_bit_cast(u32, v);
    u = (u + 0x7fffu + ((u >> 16) & 1u)) >> 16;
    dst[idx] = (unsigned short)u;
}

// ---- static-index helpers (no runtime vector subscripts anywhere) ----
template<int JB>
__device__ __forceinline__ void gcn_store(short8& t1d, short8& t2d,
                                          const short8& emo, const short8& edo,
                                          f32x4 gm, f32x4 gd, float pa, float pb) {
#define GCN_Q(Qi)                                                          \
    { float vm = pa * gm[Qi] + pb * gd[Qi];                                \
      float vd = pb * gm[Qi] + pa * gd[Qi];                                \
      vm = vm > 0.f ? vm : 0.f; vd = vd > 0.f ? vd : 0.f;                  \
      t1d[JB + Qi] = bf16rne(vm + bf2f(emo[JB + Qi]));                     \
      t2d[JB + Qi] = bf16rne(vd + bf2f(edo[JB + Qi])); }
    GCN_Q(0) GCN_Q(1) GCN_Q(2) GCN_Q(3)
#undef GCN_Q
}

template<int JB>
__device__ __forceinline__ void dot_acc(f32x4 a, const short8& e, const short8& t,
                                        float& l0, float& l1) {
    l0 += a[0] * bf2f(e[JB + 0]) + a[1] * bf2f(e[JB + 1])
        + a[2] * bf2f(e[JB + 2]) + a[3] * bf2f(e[JB + 3]);
    l1 += a[0] * bf2f(t[JB + 0]) + a[1] * bf2f(t[JB + 1])
        + a[2] * bf2f(t[JB + 2]) + a[3] * bf2f(t[JB + 3]);
}

template<int JB>
__device__ __forceinline__ void store4(short8& d, f32x4 a) {
    d[JB + 0] = bf16rne(a[0]); d[JB + 1] = bf16rne(a[1]);
    d[JB + 2] = bf16rne(a[2]); d[JB + 3] = bf16rne(a[3]);
}

template<int JB>
__device__ __forceinline__ void mul_store(short8& d, const short8& mla, f32x4 a) {
    d[JB + 0] = bf16rne(bf2f(mla[JB + 0]) * a[0]);
    d[JB + 1] = bf16rne(bf2f(mla[JB + 1]) * a[1]);
    d[JB + 2] = bf16rne(bf2f(mla[JB + 2]) * a[2]);
    d[JB + 3] = bf16rne(bf2f(mla[JB + 3]) * a[3]);
}

__device__ __forceinline__ short8 mix8(const short8& prev, const short8& cur,
                                       float aw0, float aw1) {
    short8 r;
    r[0] = bf16rne(aw0 * bf2f(prev[0]) + aw1 * bf2f(cur[0]));
    r[1] = bf16rne(aw0 * bf2f(prev[1]) + aw1 * bf2f(cur[1]));
    r[2] = bf16rne(aw0 * bf2f(prev[2]) + aw1 * bf2f(cur[2]));
    r[3] = bf16rne(aw0 * bf2f(prev[3]) + aw1 * bf2f(cur[3]));
    r[4] = bf16rne(aw0 * bf2f(prev[4]) + aw1 * bf2f(cur[4]));
    r[5] = bf16rne(aw0 * bf2f(prev[5]) + aw1 * bf2f(cur[5]));
    r[6] = bf16rne(aw0 * bf2f(prev[6]) + aw1 * bf2f(cur[6]));
    r[7] = bf16rne(aw0 * bf2f(prev[7]) + aw1 * bf2f(cur[7]));
    return r;
}

// stats + bf16 pack for one 32-col slot (two f32x4 halves), non-temporal loads
__device__ __forceinline__ void load_slot(const float* pm, const float* pd,
                                          short8& e8m, short8& e8d,
                                          float& s_mm, float& s_dd,
                                          float& s_md, float& s_ab) {
    f32x4 a0 = __builtin_nontemporal_load((const f32x4*)pm);
    f32x4 a1 = __builtin_nontemporal_load((const f32x4*)(pm + 16));
    f32x4 b0 = __builtin_nontemporal_load((const f32x4*)pd);
    f32x4 b1 = __builtin_nontemporal_load((const f32x4*)(pd + 16));
#define ST(Av, Bv, Ii)                                                     \
    s_mm += Av[Ii] * Av[Ii]; s_dd += Bv[Ii] * Bv[Ii];                      \
    s_md += Av[Ii] * Bv[Ii]; s_ab += fabsf(Av[Ii] - Bv[Ii]);
    ST(a0, b0, 0) ST(a0, b0, 1) ST(a0, b0, 2) ST(a0, b0, 3)
    ST(a1, b1, 0) ST(a1, b1, 1) ST(a1, b1, 2) ST(a1, b1, 3)
#undef ST
    e8m[0] = bf16rne(a0[0]); e8m[1] = bf16rne(a0[1]);
    e8m[2] = bf16rne(a0[2]); e8m[3] = bf16rne(a0[3]);
    e8m[4] = bf16rne(a1[0]); e8m[5] = bf16rne(a1[1]);
    e8m[6] = bf16rne(a1[2]); e8m[7] = bf16rne(a1[3]);
    e8d[0] = bf16rne(b0[0]); e8d[1] = bf16rne(b0[1]);
    e8d[2] = bf16rne(b0[2]); e8d[3] = bf16rne(b0[3]);
    e8d[4] = bf16rne(b1[0]); e8d[5] = bf16rne(b1[1]);
    e8d[6] = bf16rne(b1[2]); e8d[7] = bf16rne(b1[3]);
}

__global__ __launch_bounds__(256)
__attribute__((amdgpu_waves_per_eu(2, 4)))
void k_main(const float* __restrict__ em, const float* __restrict__ ed,
            const unsigned short* __restrict__ frags,
            const float* __restrict__ w2, float* __restrict__ out) {
    __shared__ short8 lfr[2048];                       // 32 KB single staging buffer
    const int tid  = threadIdx.x;
    const int lane = tid & 63;
    const int g    = (lane >> 4) & 3;                  // k-group / col sub-offset
    const int rs   = lane & 15;                        // row within wave
    const int wv   = tid >> 6;                         // wave in block
    const long row = ((long)blockIdx.x * 4 + wv) * 16 + rs;
    const float* emr = em + row * 128;
    const float* edr = ed + row * 128;

    // stage matrix `mat` (32 KB) into lfr; LDS dest wave-uniform base + lane*16
    auto STAGE = [&](int mat) {
        const unsigned short* src = frags + mat * 16384;
        unsigned short* lb = (unsigned short*)lfr;
#pragma unroll
        for (int w = 0; w < 8; ++w) {
            const int ch = wv * 8 + w;                 // 32 chunks x 1 KB
            __builtin_amdgcn_global_load_lds(
                (const __attribute__((address_space(1))) u32*)(src + ch * 512 + lane * 8),
                (__attribute__((address_space(3))) u32*)(lb + ch * 512), 16, 0, 0);
        }
    };

    STAGE(0);                                          // W_gcn, overlaps em/ed stream

    // ---- load em/ed (slot order), adjacency stats on the fly ----
    short8 em_0, em_1, em_2, em_3, ed_0, ed_1, ed_2, ed_3;
    float s_mm = 0.f, s_dd = 0.f, s_md = 0.f, s_ab = 0.f;
    load_slot(emr +  0 + 4 * g, edr +  0 + 4 * g, em_0, ed_0, s_mm, s_dd, s_md, s_ab);
    SBAR0;
    load_slot(emr + 32 + 4 * g, edr + 32 + 4 * g, em_1, ed_1, s_mm, s_dd, s_md, s_ab);
    SBAR0;
    load_slot(emr + 64 + 4 * g, edr + 64 + 4 * g, em_2, ed_2, s_mm, s_dd, s_md, s_ab);
    SBAR0;
    load_slot(emr + 96 + 4 * g, edr + 96 + 4 * g, em_3, ed_3, s_mm, s_dd, s_md, s_ab);
    SBAR0;

    // per-row reduce across the 4 g-groups (lanes l, l^16, l^32, l^48)
    s_mm += __shfl_xor(s_mm, 16); s_mm += __shfl_xor(s_mm, 32);
    s_dd += __shfl_xor(s_dd, 16); s_dd += __shfl_xor(s_dd, 32);
    s_md += __shfl_xor(s_md, 16); s_md += __shfl_xor(s_md, 32);
    s_ab += __shfl_xor(s_ab, 16); s_ab += __shfl_xor(s_ab, 32);

    // adjacency closed form: pL = min(pL_cos, pL_manh), both [[a,b],[b,a]]
    const float a3 = 1.f / (1.f + s_ab);               // manh off-diag >=0, lrelu=id
    const float b3 = s_ab * a3;
    float cosv = s_md * rsqrtf((s_mm + 1e-8f) * (s_dd + 1e-8f));
    float cl = cosv < 0.f ? 0.01f * cosv : cosv;       // leaky_relu 0.01
    const float a1n = 1.f / (1.f + cl);
    const float b1 = cl * a1n;
    const float pa = fminf(a1n, a3);
    const float pb = fminf(b1, b3);

    __syncthreads();                                   // W_gcn staged

    // one C-column-block GEMM: a += frag(cb,m) * x_m
#define GEMM8(CB, X0, X1, X2, X3, A)                                       \
    { A = MF(lfr[((CB) * 4 + 0) * 64 + lane], X0, A);                      \
      A = MF(lfr[((CB) * 4 + 1) * 64 + lane], X1, A);                      \
      A = MF(lfr[((CB) * 4 + 2) * 64 + lane], X2, A);                      \
      A = MF(lfr[((CB) * 4 + 3) * 64 + lane], X3, A); }

    // ---- GCN: gm=em@W, gd=ed@W from ORIGINALS; x1 -> x1m_*/x1d_* ----
    short8 x1m_0, x1m_1, x1m_2, x1m_3, x1d_0, x1d_1, x1d_2, x1d_3;
#define SEC_GCN(CB, JB, T1D, T2D, EMO, EDO)                                \
    { f32x4 gm = {0.f, 0.f, 0.f, 0.f}, gd = {0.f, 0.f, 0.f, 0.f};          \
      { const short8 w0 = lfr[((CB) * 4 + 0) * 64 + lane];                 \
        const short8 w1 = lfr[((CB) * 4 + 1) * 64 + lane];                 \
        const short8 wA = lfr[((CB) * 4 + 2) * 64 + lane];                 \
        const short8 wB = lfr[((CB) * 4 + 3) * 64 + lane];                 \
        gm = MF(w0, em_0, gm); gd = MF(w0, ed_0, gd);                      \
        gm = MF(w1, em_1, gm); gd = MF(w1, ed_1, gd);                      \
        gm = MF(wA, em_2, gm); gd = MF(wA, ed_2, gd);                      \
        gm = MF(wB, em_3, gm); gd = MF(wB, ed_3, gd); }                    \
      gcn_store<JB>(T1D, T2D, EMO, EDO, gm, gd, pa, pb); }                 \
    SBAR0;
    SEC_GCN(0, 0, x1m_0, x1d_0, em_0, ed_0)
    SEC_GCN(1, 4, x1m_0, x1d_0, em_0, ed_0)
    SEC_GCN(2, 0, x1m_1, x1d_1, em_1, ed_1)
    SEC_GCN(3, 4, x1m_1, x1d_1, em_1, ed_1)
    SEC_GCN(4, 0, x1m_2, x1d_2, em_2, ed_2)
    SEC_GCN(5, 4, x1m_2, x1d_2, em_2, ed_2)
    SEC_GCN(6, 0, x1m_3, x1d_3, em_3, ed_3)
    SEC_GCN(7, 4, x1m_3, x1d_3, em_3, ed_3)
#undef SEC_GCN

    __syncthreads(); STAGE(1); __syncthreads();        // M_m

    const float isq = 0.08838834764831845f;            // 1/sqrt(128)

    // ---- m attention: logits via t = x1_m@M_m ----
    float l0 = 0.f, l1 = 0.f;
#define SEC_LOG(CB, JB, EO, TT, LA, LB)                                    \
    { f32x4 a = {0.f, 0.f, 0.f, 0.f};                                      \
      GEMM8(CB, x1m_0, x1m_1, x1m_2, x1m_3, a)                             \
      dot_acc<JB>(a, EO, TT, LA, LB); }                                    \
    SBAR0;
    SEC_LOG(0, 0, em_0, x1m_0, l0, l1)
    SEC_LOG(1, 4, em_0, x1m_0, l0, l1)
    SEC_LOG(2, 0, em_1, x1m_1, l0, l1)
    SEC_LOG(3, 4, em_1, x1m_1, l0, l1)
    SEC_LOG(4, 0, em_2, x1m_2, l0, l1)
    SEC_LOG(5, 4, em_2, x1m_2, l0, l1)
    SEC_LOG(6, 0, em_3, x1m_3, l0, l1)
    SEC_LOG(7, 4, em_3, x1m_3, l0, l1)
#undef SEC_LOG
    l0 += __shfl_xor(l0, 16); l0 += __shfl_xor(l0, 32);
    l1 += __shfl_xor(l1, 16); l1 += __shfl_xor(l1, 32);
    l0 *= isq; l1 *= isq;
    {
        float mx = fmaxf(l0, l1);
        float e0 = __expf(l0 - mx), e1 = __expf(l1 - mx);
        float inv = 1.f / (e0 + e1);
        float aw0 = e0 * inv, aw1 = e1 * inv;
        x1m_0 = mix8(em_0, x1m_0, aw0, aw1);
        x1m_1 = mix8(em_1, x1m_1, aw0, aw1);
        x1m_2 = mix8(em_2, x1m_2, aw0, aw1);
        x1m_3 = mix8(em_3, x1m_3, aw0, aw1);
    }
    __syncthreads(); STAGE(2); __syncthreads();        // Wv_m

    // ---- mLA = mix@Wv_m -> em_* (em dead past this point) ----
#define SEC_MLA(CB, JB, DEST)                                              \
    { f32x4 a = {0.f, 0.f, 0.f, 0.f};                                      \
      GEMM8(CB, x1m_0, x1m_1, x1m_2, x1m_3, a)                             \
      store4<JB>(DEST, a); }                                               \
    SBAR0;
    SEC_MLA(0, 0, em_0) SEC_MLA(1, 4, em_0)
    SEC_MLA(2, 0, em_1) SEC_MLA(3, 4, em_1)
    SEC_MLA(4, 0, em_2) SEC_MLA(5, 4, em_2)
    SEC_MLA(6, 0, em_3) SEC_MLA(7, 4, em_3)
#undef SEC_MLA
    __syncthreads(); STAGE(3); __syncthreads();        // M_d

    // ---- d attention ----
    float l0d = 0.f, l1d = 0.f;
#define SEC_LOGD(CB, JB, EO, TT)                                           \
    { f32x4 a = {0.f, 0.f, 0.f, 0.f};                                      \
      GEMM8(CB, x1d_0, x1d_1, x1d_2, x1d_3, a)                             \
      dot_acc<JB>(a, EO, TT, l0d, l1d); }                                  \
    SBAR0;
    SEC_LOGD(0, 0, ed_0, x1d_0)
    SEC_LOGD(1, 4, ed_0, x1d_0)
    SEC_LOGD(2, 0, ed_1, x1d_1)
    SEC_LOGD(3, 4, ed_1, x1d_1)
    SEC_LOGD(4, 0, ed_2, x1d_2)
    SEC_LOGD(5, 4, ed_2, x1d_2)
    SEC_LOGD(6, 0, ed_3, x1d_3)
    SEC_LOGD(7, 4, ed_3, x1d_3)
#undef SEC_LOGD
    l0d += __shfl_xor(l0d, 16); l0d += __shfl_xor(l0d, 32);
    l1d += __shfl_xor(l1d, 16); l1d += __shfl_xor(l1d, 32);
    l0d *= isq; l1d *= isq;
    {
        float mx = fmaxf(l0d, l1d);
        float e0 = __expf(l0d - mx), e1 = __expf(l1d - mx);
        float inv = 1.f / (e0 + e1);
        float aw0 = e0 * inv, aw1 = e1 * inv;
        x1d_0 = mix8(ed_0, x1d_0, aw0, aw1);
        x1d_1 = mix8(ed_1, x1d_1, aw0, aw1);
        x1d_2 = mix8(ed_2, x1d_2, aw0, aw1);
        x1d_3 = mix8(ed_3, x1d_3, aw0, aw1);
    }
    __syncthreads(); STAGE(4); __syncthreads();        // Wv_d

    // ---- dLA fused with ne = mLA*dLA -> x1m_* ----
#define SEC_DLA(CB, JB, MLA, DEST)                                         \
    { f32x4 a = {0.f, 0.f, 0.f, 0.f};                                      \
      GEMM8(CB, x1d_0, x1d_1, x1d_2, x1d_3, a)                             \
      mul_store<JB>(DEST, MLA, a); }                                       \
    SBAR0;
    SEC_DLA(0, 0, em_0, x1m_0) SEC_DLA(1, 4, em_0, x1m_0)
    SEC_DLA(2, 0, em_1, x1m_1) SEC_DLA(3, 4, em_1, x1m_1)
    SEC_DLA(4, 0, em_2, x1m_2) SEC_DLA(5, 4, em_2, x1m_2)
    SEC_DLA(6, 0, em_3, x1m_3) SEC_DLA(7, 4, em_3, x1m_3)
#undef SEC_DLA
    __syncthreads(); STAGE(5); __syncthreads();        // W1

    // ---- head: pre = relu(ne@W1) . w2 ; out = sigmoid(pre) ----
    float pre = 0.f;
#define SEC_HEAD(CB)                                                       \
    { f32x4 a = {0.f, 0.f, 0.f, 0.f};                                      \
      GEMM8(CB, x1m_0, x1m_1, x1m_2, x1m_3, a)                             \
      f32x4 wq = *(const f32x4*)(w2 + 16 * (CB) + 4 * g);                  \
      pre += fmaxf(a[0], 0.f) * wq[0] + fmaxf(a[1], 0.f) * wq[1]           \
           + fmaxf(a[2], 0.f) * wq[2] + fmaxf(a[3], 0.f) * wq[3]; }        \
    SBAR0;
    SEC_HEAD(0) SEC_HEAD(1) SEC_HEAD(2) SEC_HEAD(3)
    SEC_HEAD(4) SEC_HEAD(5) SEC_HEAD(6) SEC_HEAD(7)
#undef SEC_HEAD
#undef GEMM8
    pre += __shfl_xor(pre, 16); pre += __shfl_xor(pre, 32);
    if (g == 0) out[row] = 1.f / (1.f + __expf(-pre));
}

extern "C" void kernel_launch(void* const* d_in, const int* in_sizes, int n_in,
                              void* d_out, int out_size, void* d_ws, size_t ws_size,
                              hipStream_t stream) {
    const float* em    = (const float*)d_in[0];
    const float* ed    = (const float*)d_in[1];
    const float* W_gcn = (const float*)d_in[2];
    const float* Wq_m  = (const float*)d_in[3];
    const float* Wk_m  = (const float*)d_in[4];
    const float* Wv_m  = (const float*)d_in[5];
    const float* Wq_d  = (const float*)d_in[6];
    const float* Wk_d  = (const float*)d_in[7];
    const float* Wv_d  = (const float*)d_in[8];
    const float* W1    = (const float*)d_in[9];
    const float* W2    = (const float*)d_in[10];
    float* out = (float*)d_out;

    unsigned short* frags = (unsigned short*)d_ws;     // 6*16384 bf16 = 192 KB

    const int B = in_sizes[0] / 128;                   // 262144

    hipLaunchKernelGGL(k_pack, dim3(384), dim3(256), 0, stream,
                       W_gcn, Wq_m, Wk_m, Wv_m, Wq_d, Wk_d, Wv_d, W1, frags);
    hipLaunchKernelGGL(k_main, dim3(B / 64), dim3(256), 0, stream,
                       em, ed, frags, W2, out);
}